// Round 9
// baseline (246.446 us; speedup 1.0000x reference)
//
#include <hip/hip_runtime.h>
#include <math.h>

// Problem constants: B=8, C=d=384, H=32, W=32 -> N=1024 tokens, HEADS=8, dh=48
#define NTOK 1024
#define DM   384
#define NHEAD 8
#define DH   48
#define BATCH 8
#define NROWS (BATCH * NTOK)   // 8192 token rows
#define SC2   (0.14433756729740643f * 1.4426950408889634f)   // (1/sqrt(48)) * log2(e)

typedef __attribute__((ext_vector_type(8))) _Float16 f16x8;
typedef __attribute__((ext_vector_type(2))) __fp16 fp16x2_raw;
typedef __attribute__((ext_vector_type(4))) float f32x4;

#define ASYNC16(gp, lp) __builtin_amdgcn_global_load_lds( \
    (const __attribute__((address_space(1))) void*)(gp),  \
    (__attribute__((address_space(3))) void*)(lp), 16, 0, 0)

__device__ __forceinline__ unsigned int pkh(float a, float b) {
    union { fp16x2_raw h; unsigned int u; } cv;
    cv.h = __builtin_amdgcn_cvt_pkrtz(a, b);
    return cv.u;
}

// tanh-form GELU via exp2 (max dev from exact erf ~3e-3 << 0.104 threshold)
__device__ __forceinline__ float gelu_fast(float v) {
    const float u = v * (0.7978845608f + 0.0356774081f * v * v);
    const float e = exp2f(u * 2.885390082f);
    return v * e / (e + 1.0f);
}

// ============ prep: (bid<256) transpose x + double-LN -> t fp32, a_h fp16 ============
// ============       (bid>=256) weight transpose+cast fp32 -> fp16 [N][K]  ============
__global__ __launch_bounds__(256) void prep_kernel(const float* __restrict__ x,
                                                   const float* __restrict__ ln1_g,
                                                   const float* __restrict__ ln1_b,
                                                   const float* __restrict__ lna_g,
                                                   const float* __restrict__ lna_b,
                                                   float* __restrict__ t,
                                                   _Float16* __restrict__ a_h,
                                                   const float* __restrict__ wqkv,
                                                   const float* __restrict__ wout,
                                                   const float* __restrict__ w1,
                                                   const float* __restrict__ w2,
                                                   _Float16* __restrict__ wqkvT,
                                                   _Float16* __restrict__ woutT,
                                                   _Float16* __restrict__ w1T,
                                                   _Float16* __restrict__ w2T) {
    __shared__ float Ts[32][389];
    const int bid = blockIdx.x;
    const int tid = threadIdx.x;

    if (bid >= 256) {
        float (*tile)[33] = (float(*)[33])&Ts[0][0];
        const int wb = bid - 256;
        const float* W; _Float16* Wt; int K, N, nx, tt;
        if (wb < 432)       { W = wqkv; Wt = wqkvT; K = 384;  N = 1152; nx = 36; tt = wb; }
        else if (wb < 576)  { W = wout; Wt = woutT; K = 384;  N = 384;  nx = 12; tt = wb - 432; }
        else if (wb < 1152) { W = w1;   Wt = w1T;   K = 384;  N = 1536; nx = 48; tt = wb - 576; }
        else                { W = w2;   Wt = w2T;   K = 1536; N = 384;  nx = 12; tt = wb - 1152; }
        const int n0 = (tt % nx) * 32, k0 = (tt / nx) * 32;
        const int tx = tid & 31, ty = tid >> 5;
        #pragma unroll
        for (int i = ty; i < 32; i += 8)
            tile[i][tx] = W[(size_t)(k0 + i) * N + n0 + tx];
        __syncthreads();
        #pragma unroll
        for (int i = ty; i < 32; i += 8)
            Wt[(size_t)(n0 + i) * K + k0 + tx] = (_Float16)tile[tx][i];
        return;
    }

    // ---- transpose + double-LN ----
    const int b = bid >> 5, n0 = (bid & 31) * 32;
    const int tx = tid & 31, ty8 = tid >> 5;
    const float* xb = x + (size_t)b * (DM * NTOK);
    #pragma unroll
    for (int c0 = 0; c0 < DM; c0 += 32) {
        #pragma unroll
        for (int i = ty8; i < 32; i += 8)
            Ts[tx][c0 + i] = xb[(size_t)(c0 + i) * NTOK + n0 + tx];
    }
    __syncthreads();

    const int g = tid >> 3, sub = tid & 7;
    const int c0 = sub * 48;
    float xv[48];
    #pragma unroll
    for (int k = 0; k < 12; ++k)
        *(float4*)&xv[k * 4] = *(const float4*)&Ts[g][c0 + k * 4];

    const size_t trow = (size_t)((b << 10) + n0 + g) * DM;
    float s = 0.0f, sq = 0.0f;
    #pragma unroll
    for (int k = 0; k < 12; ++k)
        *(float4*)&t[trow + c0 + k * 4] = *(const float4*)&xv[k * 4];
    #pragma unroll
    for (int j = 0; j < 48; ++j) { s += xv[j]; sq += xv[j] * xv[j]; }
    s += __shfl_xor(s, 1, 64); sq += __shfl_xor(sq, 1, 64);
    s += __shfl_xor(s, 2, 64); sq += __shfl_xor(sq, 2, 64);
    s += __shfl_xor(s, 4, 64); sq += __shfl_xor(sq, 4, 64);
    float mu = s * (1.0f / DM);
    float var = fmaxf(sq * (1.0f / DM) - mu * mu, 0.0f);
    float r1 = rsqrtf(var + 1e-5f);

    float s2 = 0.0f, q2 = 0.0f;
    #pragma unroll
    for (int k = 0; k < 12; ++k) {
        const float4 gk = *(const float4*)&ln1_g[c0 + k * 4];
        const float4 bk = *(const float4*)&ln1_b[c0 + k * 4];
        float y0 = (xv[k*4+0] - mu) * r1 * gk.x + bk.x;
        float y1 = (xv[k*4+1] - mu) * r1 * gk.y + bk.y;
        float y2 = (xv[k*4+2] - mu) * r1 * gk.z + bk.z;
        float y3 = (xv[k*4+3] - mu) * r1 * gk.w + bk.w;
        xv[k*4+0] = y0; xv[k*4+1] = y1; xv[k*4+2] = y2; xv[k*4+3] = y3;
        s2 += (y0 + y1) + (y2 + y3);
        q2 += (y0*y0 + y1*y1) + (y2*y2 + y3*y3);
    }
    s2 += __shfl_xor(s2, 1, 64); q2 += __shfl_xor(q2, 1, 64);
    s2 += __shfl_xor(s2, 2, 64); q2 += __shfl_xor(q2, 2, 64);
    s2 += __shfl_xor(s2, 4, 64); q2 += __shfl_xor(q2, 4, 64);
    mu = s2 * (1.0f / DM);
    var = fmaxf(q2 * (1.0f / DM) - mu * mu, 0.0f);
    const float r2 = rsqrtf(var + 1e-5f);

    unsigned int d[12];
    #pragma unroll
    for (int k = 0; k < 12; ++k) {
        const float4 gk = *(const float4*)&lna_g[c0 + k * 4];
        const float4 bk = *(const float4*)&lna_b[c0 + k * 4];
        const float y0 = (xv[k*4+0] - mu) * r2 * gk.x + bk.x;
        const float y1 = (xv[k*4+1] - mu) * r2 * gk.y + bk.y;
        const float y2 = (xv[k*4+2] - mu) * r2 * gk.z + bk.z;
        const float y3 = (xv[k*4+3] - mu) * r2 * gk.w + bk.w;
        d[k*2+0] = pkh(y0, y1); d[k*2+1] = pkh(y2, y3);
    }
    unsigned int* op = (unsigned int*)(a_h + trow + c0);
    #pragma unroll
    for (int k = 0; k < 3; ++k)
        *(uint4*)(op + k * 4) = *(const uint4*)&d[k * 4];
}

// ---------------- layernorm2: one wave per row (fp32 in, fp16 out) ----------------
__global__ __launch_bounds__(256) void ln2_kernel(const float* __restrict__ in,
                                                  const float* __restrict__ gg,
                                                  const float* __restrict__ bb,
                                                  _Float16* __restrict__ outp) {
    const int row = blockIdx.x * 4 + (threadIdx.x >> 6);
    const int lane = threadIdx.x & 63;
    const float* ip = in + (size_t)row * DM + lane * 6;
    float v[6];
    *(float2*)&v[0] = *(const float2*)(ip);
    *(float2*)&v[2] = *(const float2*)(ip + 2);
    *(float2*)&v[4] = *(const float2*)(ip + 4);
    float s = 0.0f, sq = 0.0f;
    #pragma unroll
    for (int j = 0; j < 6; ++j) { s += v[j]; sq += v[j] * v[j]; }
    #pragma unroll
    for (int off = 1; off < 64; off <<= 1) {
        s += __shfl_xor(s, off, 64);
        sq += __shfl_xor(sq, off, 64);
    }
    const float mu = s * (1.0f / DM);
    const float var = fmaxf(sq * (1.0f / DM) - mu * mu, 0.0f);
    const float rs = rsqrtf(var + 1e-5f);
    const float* gp = gg + lane * 6;
    const float* bp = bb + lane * 6;
    float y[6];
    #pragma unroll
    for (int j = 0; j < 6; ++j) y[j] = (v[j] - mu) * rs * gp[j] + bp[j];
    unsigned int* op = (unsigned int*)(outp + (size_t)row * DM + lane * 6);
    op[0] = pkh(y[0], y[1]); op[1] = pkh(y[2], y[3]); op[2] = pkh(y[4], y[5]);
}

// ---------------- fp16 MFMA GEMM, single-barrier double-buffered pipeline ----------------
// C = A[M,K] @ Bt[N,K]^T.  EPI: 0 plain->fp16; 1 +residual->fp32; 2 +bias,GELU->fp16;
// 5 split-K partial -> fp32 (blockIdx.z selects K-half and partial buffer, N=384).
template <int EPI, int BN>
__global__ __launch_bounds__(256) void gemm_f16(const _Float16* __restrict__ A,
                                                const _Float16* __restrict__ Bt,
                                                const float* __restrict__ bias,
                                                const float* __restrict__ R,
                                                _Float16* __restrict__ Ch,
                                                float* __restrict__ Cf,
                                                int M, int N, int K) {
    constexpr int NFRAG = BN / 32;
    constexpr int BSTG = BN / 32;
    __shared__ _Float16 As[2][128][64];
    __shared__ _Float16 Bs[2][BN][64];
    const int tid = threadIdx.x;
    const int w = tid >> 6, lane = tid & 63;
    const int l15 = lane & 15, lq = lane >> 4;
    const int bm = blockIdx.y * 128, bn = blockIdx.x * BN;
    const int moff = (w & 1) * 64, noff = (w >> 1) * (BN / 2);

    const int kspan = (EPI == 5) ? (K >> 1) : K;
    const int zoff = (EPI == 5) ? blockIdx.z * kspan : 0;

    const int srw = lane >> 3, pp = lane & 7;
    const int c = pp ^ srw;
    const _Float16* Ag[4];
    const _Float16* Bg[BSTG];
    #pragma unroll
    for (int j = 0; j < 4; ++j)
        Ag[j] = A + (size_t)(bm + w * 32 + j * 8 + srw) * K + zoff + c * 8;
    #pragma unroll
    for (int j = 0; j < BSTG; ++j)
        Bg[j] = Bt + (size_t)(bn + w * (BN / 4) + j * 8 + srw) * K + zoff + c * 8;

    const int octA = ((lq ^ (l15 & 7)) << 4);

    f32x4 acc[4][NFRAG];
    #pragma unroll
    for (int mi = 0; mi < 4; ++mi)
        #pragma unroll
        for (int ni = 0; ni < NFRAG; ++ni) acc[mi][ni] = (f32x4){0.f, 0.f, 0.f, 0.f};

    // prologue: prefetch tile 0 into buf 0
    #pragma unroll
    for (int j = 0; j < 4; ++j) { ASYNC16(Ag[j], &As[0][w * 32 + j * 8][0]); Ag[j] += 64; }
    #pragma unroll
    for (int j = 0; j < BSTG; ++j) { ASYNC16(Bg[j], &Bs[0][w * (BN / 4) + j * 8][0]); Bg[j] += 64; }

    int cur = 0;
    for (int k0 = 64; k0 <= kspan; k0 += 64) {
        __syncthreads();
        if (k0 < kspan) {
            #pragma unroll
            for (int j = 0; j < 4; ++j) { ASYNC16(Ag[j], &As[cur ^ 1][w * 32 + j * 8][0]); Ag[j] += 64; }
            #pragma unroll
            for (int j = 0; j < BSTG; ++j) { ASYNC16(Bg[j], &Bs[cur ^ 1][w * (BN / 4) + j * 8][0]); Bg[j] += 64; }
        }
        const char* Ab = (const char*)&As[cur][0][0];
        const char* Bb = (const char*)&Bs[cur][0][0];
        #pragma unroll
        for (int ks = 0; ks < 2; ++ks) {
            const int ox = octA ^ (ks << 6);
            f16x8 af[4], bfr[NFRAG];
            #pragma unroll
            for (int mi = 0; mi < 4; ++mi)
                af[mi] = *(const f16x8*)(Ab + ((moff + mi * 16 + l15) << 7) + ox);
            #pragma unroll
            for (int ni = 0; ni < NFRAG; ++ni)
                bfr[ni] = *(const f16x8*)(Bb + ((noff + ni * 16 + l15) << 7) + ox);
            #pragma unroll
            for (int mi = 0; mi < 4; ++mi)
                #pragma unroll
                for (int ni = 0; ni < NFRAG; ++ni)
                    acc[mi][ni] = __builtin_amdgcn_mfma_f32_16x16x32_f16(af[mi], bfr[ni], acc[mi][ni], 0, 0, 0);
        }
        cur ^= 1;
    }

    // epilogue
    float* Cfz = (EPI == 5) ? (Cf + (size_t)blockIdx.z * NROWS * 384) : Cf;
    #pragma unroll
    for (int mi = 0; mi < 4; ++mi) {
        #pragma unroll
        for (int ni = 0; ni < NFRAG; ++ni) {
            const int col = bn + noff + ni * 16 + l15;
            float bv = 0.0f;
            if (EPI == 2) bv = bias[col];
            #pragma unroll
            for (int r = 0; r < 4; ++r) {
                const int row = bm + moff + mi * 16 + lq * 4 + r;
                const size_t idx = (size_t)row * N + col;
                float v = acc[mi][ni][r];
                if (EPI == 2) v = gelu_fast(v + bv);
                if (EPI == 0 || EPI == 2) Ch[idx] = (_Float16)v;
                else if (EPI == 1)        Cf[idx] = v + R[idx];
                else                      Cfz[idx] = v;
            }
        }
    }
}

// ---------------- merge: out[b,c,n] = p0+p1+b2[c]+t, transposed write ----------------
__global__ __launch_bounds__(256) void merge_kernel(const float* __restrict__ p0,
                                                    const float* __restrict__ p1,
                                                    const float* __restrict__ t,
                                                    const float* __restrict__ b2,
                                                    float* __restrict__ out) {
    __shared__ float tile[32][33];
    const int b = blockIdx.z, n0 = blockIdx.y * 32, c0 = blockIdx.x * 32;
    const int tx = threadIdx.x & 31, ty = threadIdx.x >> 5;
    const float bv = b2[c0 + tx];
    #pragma unroll
    for (int i = ty; i < 32; i += 8) {
        const size_t idx = (size_t)((b << 10) + n0 + i) * DM + c0 + tx;
        tile[i][tx] = p0[idx] + p1[idx] + t[idx] + bv;
    }
    __syncthreads();
    #pragma unroll
    for (int i = ty; i < 32; i += 8)
        out[(size_t)b * (DM * NTOK) + (size_t)(c0 + i) * NTOK + n0 + tx] = tile[tx][i];
}

// ---------------- MFMA flash attention v6 (64q, dbuf, 4 blocks/CU) ----------------
// 1024 blocks (4/CU, 16 waves/CU). Wave owns 16 q; Q in registers; K dbuf via
// global_load_lds; V dbuf via regs + deferred LDS write; 1 barrier/ktile.
__global__ __launch_bounds__(256) void attn_kernel(const _Float16* __restrict__ qkv,
                                                   _Float16* __restrict__ o) {
    __shared__ _Float16 Ks[2][64][64];   // 16 KB
    __shared__ _Float16 Vt[2][48][72];   // 13.8 KB
    __shared__ _Float16 Ps[4][16][72];   // 9.2 KB  -> ~39 KB total
    const int tid = threadIdx.x;
    const int w = tid >> 6, lane = tid & 63;
    const int l15 = lane & 15, lq = lane >> 4;
    const int bid = blockIdx.x;
    const int bh = ((bid >> 3) & 7) * 8 + (bid & 7);   // same (b,h) -> same XCD (mod-8)
    const int qt0 = (bid >> 6) * 64;
    const int h = bh & 7, b = bh >> 3;

    const _Float16* qbase = qkv + (size_t)b * NTOK * 1152 + h * 48;
    const _Float16* kbase = qbase + 384;
    const _Float16* vbase = qbase + 768;

    // ---- Q fragments in registers (feat >= 48 zero -> kills K-pad garbage) ----
    f16x8 qf[2];
    {
        const size_t qrow = (size_t)(qt0 + w * 16 + l15) * 1152;
        qf[0] = *(const f16x8*)(qbase + qrow + lq * 8);
        if (lq < 2) qf[1] = *(const f16x8*)(qbase + qrow + 32 + lq * 8);
        else        qf[1] = (f16x8){(_Float16)0, (_Float16)0, (_Float16)0, (_Float16)0,
                                    (_Float16)0, (_Float16)0, (_Float16)0, (_Float16)0};
    }

    const int srw = lane >> 3, pp = lane & 7;
    const int ck = pp ^ srw;
    const int ckoff = (ck < 6) ? ck * 8 : (ck - 6) * 8;
    const _Float16* Kg = kbase + (size_t)(w * 16 + srw) * 1152 + ckoff;
    const int vtp = tid & 31, vfo = tid >> 5;
    const _Float16* Vg = vbase + (size_t)(vtp * 2) * 1152 + vfo * 8;

    const int octK = ((lq ^ (l15 & 7)) << 4);

    // prologue: prefetch tile 0
    ASYNC16(Kg, &Ks[0][w * 16][0]);
    ASYNC16(Kg + 8 * 1152, &Ks[0][w * 16 + 8][0]);
    Kg += 64 * 1152;
    uint4 va, vb;
    if (vfo < 6) { va = *(const uint4*)Vg; vb = *(const uint4*)(Vg + 1152); }
    Vg += 64 * 1152;

    f32x4 oacc[3];
    float lpart = 0.0f;
    #pragma unroll
    for (int vf = 0; vf < 3; ++vf) oacc[vf] = (f32x4){0.f, 0.f, 0.f, 0.f};

    int cur = 0;
    for (int kt = 0; kt < 16; ++kt) {
        if (vfo < 6) {   // deferred V write (vmcnt wait lands after prev compute)
            const unsigned short* as = (const unsigned short*)&va;
            const unsigned short* bs = (const unsigned short*)&vb;
            #pragma unroll
            for (int j = 0; j < 8; ++j) {
                const unsigned int dw = (unsigned int)as[j] | ((unsigned int)bs[j] << 16);
                *(unsigned int*)((char*)&Vt[cur][0][0] + (vfo * 8 + j) * 144 + vtp * 4) = dw;
            }
        }
        __syncthreads();
        if (kt < 15) {
            ASYNC16(Kg, &Ks[cur ^ 1][w * 16][0]);
            ASYNC16(Kg + 8 * 1152, &Ks[cur ^ 1][w * 16 + 8][0]);
            Kg += 64 * 1152;
            if (vfo < 6) { va = *(const uint4*)Vg; vb = *(const uint4*)(Vg + 1152); }
            Vg += 64 * 1152;
        }

        // ---- S^T = K @ Q^T (4 kpos-tiles) ----
        f32x4 sacc[4];
        #pragma unroll
        for (int mi = 0; mi < 4; ++mi) sacc[mi] = (f32x4){0.f, 0.f, 0.f, 0.f};
        #pragma unroll
        for (int ks = 0; ks < 2; ++ks) {
            const int ox = octK ^ (ks << 6);
            #pragma unroll
            for (int mi = 0; mi < 4; ++mi) {
                const f16x8 kf = *(const f16x8*)((const char*)&Ks[cur][0][0] + ((mi * 16 + l15) << 7) + ox);
                sacc[mi] = __builtin_amdgcn_mfma_f32_16x16x32_f16(kf, qf[ks], sacc[mi], 0, 0, 0);
            }
        }

        // ---- exp2 (no max-sub), partial l, pack P (wave-private) ----
        #pragma unroll
        for (int mi = 0; mi < 4; ++mi) {
            const float p0 = exp2f(sacc[mi][0] * SC2);
            const float p1 = exp2f(sacc[mi][1] * SC2);
            const float p2 = exp2f(sacc[mi][2] * SC2);
            const float p3 = exp2f(sacc[mi][3] * SC2);
            lpart += (p0 + p1) + (p2 + p3);
            uint2 d;
            d.x = pkh(p0, p1); d.y = pkh(p2, p3);
            *(uint2*)((char*)&Ps[w][0][0] + l15 * 144 + (mi * 16 + lq * 4) * 2) = d;
        }
        asm volatile("s_waitcnt lgkmcnt(0)" ::: "memory");

        // ---- O^T += V^T @ P ----
        #pragma unroll
        for (int ks = 0; ks < 2; ++ks) {
            const int kk2 = ks * 64 + lq * 16;
            const f16x8 pf = *(const f16x8*)((const char*)&Ps[w][0][0] + l15 * 144 + kk2);
            #pragma unroll
            for (int vf = 0; vf < 3; ++vf) {
                const f16x8 vv = *(const f16x8*)((const char*)&Vt[cur][0][0] + (vf * 16 + l15) * 144 + kk2);
                oacc[vf] = __builtin_amdgcn_mfma_f32_16x16x32_f16(vv, pf, oacc[vf], 0, 0, 0);
            }
        }
        cur ^= 1;
    }

    // ---- normalize + write ----
    lpart += __shfl_xor(lpart, 16, 64);
    lpart += __shfl_xor(lpart, 32, 64);
    const float linv = 1.0f / lpart;
    _Float16* ob = o + (size_t)(b * NTOK + qt0 + w * 16 + l15) * DM + h * DH;
    #pragma unroll
    for (int vf = 0; vf < 3; ++vf) {
        uint2 d;
        d.x = pkh(oacc[vf][0] * linv, oacc[vf][1] * linv);
        d.y = pkh(oacc[vf][2] * linv, oacc[vf][3] * linv);
        *(uint2*)(ob + vf * 16 + lq * 4) = d;
    }
}

extern "C" void kernel_launch(void* const* d_in, const int* in_sizes, int n_in,
                              void* d_out, int out_size, void* d_ws, size_t ws_size,
                              hipStream_t stream) {
    const float* x     = (const float*)d_in[0];
    const float* ln1_g = (const float*)d_in[1];
    const float* ln1_b = (const float*)d_in[2];
    const float* lna_g = (const float*)d_in[3];
    const float* lna_b = (const float*)d_in[4];
    const float* w_qkv = (const float*)d_in[5];
    const float* w_out = (const float*)d_in[6];
    const float* ln2_g = (const float*)d_in[7];
    const float* ln2_b = (const float*)d_in[8];
    const float* w1    = (const float*)d_in[9];
    const float* b1    = (const float*)d_in[10];
    const float* w2    = (const float*)d_in[11];
    const float* b2    = (const float*)d_in[12];
    float* out = (float*)d_out;

    char* wsb = (char*)d_ws;
    float* t          = (float*)(wsb);                 // 12,582,912 B
    _Float16* a_h     = (_Float16*)(wsb + 12582912);   //  6,291,456
    _Float16* qkv_h   = (_Float16*)(wsb + 18874368);   // 18,874,368
    _Float16* o_h     = (_Float16*)(wsb + 37748736);   //  6,291,456
    _Float16* h1_h    = (_Float16*)(wsb + 44040192);   // 25,165,824
    _Float16* wqkvT   = (_Float16*)(wsb + 69206016);   //    884,736
    _Float16* woutT   = (_Float16*)(wsb + 70090752);   //    294,912
    _Float16* w1T     = (_Float16*)(wsb + 70385664);   //  1,179,648
    _Float16* w2T     = (_Float16*)(wsb + 71565312);   //  1,179,648
    float* p01        = (float*)(wsb + 72744960);      // 2 x 12,582,912 partials

    // 1. fused: transpose+LN+LN -> t, a_h ; weight prep -> *T
    prep_kernel<<<256 + 1728, 256, 0, stream>>>(x, ln1_g, ln1_b, lna_g, lna_b, t, a_h,
                                                w_qkv, w_out, w1, w2, wqkvT, woutT, w1T, w2T);
    // 2. qkv_h = a @ w_qkv
    gemm_f16<0, 128><<<dim3(9, 64), 256, 0, stream>>>(a_h, wqkvT, nullptr, nullptr, qkv_h, nullptr, NROWS, 3 * DM, DM);
    // 3. o_h = attention(qkv_h)
    attn_kernel<<<1024, 256, 0, stream>>>(qkv_h, o_h);
    // 4. t = t + o @ w_out
    gemm_f16<1, 64><<<dim3(6, 64), 256, 0, stream>>>(o_h, woutT, nullptr, t, nullptr, t, NROWS, DM, DM);
    // 5. a_h = fp16(LN(t))
    ln2_kernel<<<2048, 256, 0, stream>>>(t, ln2_g, ln2_b, a_h);
    // 6. h1_h = gelu(a @ w1 + b1)
    gemm_f16<2, 128><<<dim3(12, 64), 256, 0, stream>>>(a_h, w1T, b1, nullptr, h1_h, nullptr, NROWS, 4 * DM, DM);
    // 7. split-K: p01[z] = h1 @ w2 (K-half z)
    gemm_f16<5, 64><<<dim3(6, 64, 2), 256, 0, stream>>>(h1_h, w2T, nullptr, nullptr, nullptr, p01, NROWS, DM, 4 * DM);
    // 8. out = transpose(p0 + p1 + b2 + t)
    merge_kernel<<<dim3(12, 32, 8), 256, 0, stream>>>(p01, p01 + (size_t)NROWS * DM, t, b2, out);
}

// Round 10
// 226.974 us; speedup vs baseline: 1.0858x; 1.0858x over previous
//
#include <hip/hip_runtime.h>
#include <math.h>

// Problem constants: B=8, C=d=384, H=32, W=32 -> N=1024 tokens, HEADS=8, dh=48
#define NTOK 1024
#define DM   384
#define NHEAD 8
#define DH   48
#define BATCH 8
#define NROWS (BATCH * NTOK)   // 8192 token rows
#define SC2   (0.14433756729740643f * 1.4426950408889634f)   // (1/sqrt(48)) * log2(e)

typedef __attribute__((ext_vector_type(8))) _Float16 f16x8;
typedef __attribute__((ext_vector_type(2))) __fp16 fp16x2_raw;
typedef __attribute__((ext_vector_type(4))) float f32x4;

#define ASYNC16(gp, lp) __builtin_amdgcn_global_load_lds( \
    (const __attribute__((address_space(1))) void*)(gp),  \
    (__attribute__((address_space(3))) void*)(lp), 16, 0, 0)

// raw-instruction transcendentals: v_exp_f32 / v_rcp_f32 (1 instr each, ~1 ulp)
#define EXP2R(x) __builtin_amdgcn_exp2f(x)
#define RCPR(x)  __builtin_amdgcn_rcpf(x)

__device__ __forceinline__ unsigned int pkh(float a, float b) {
    union { fp16x2_raw h; unsigned int u; } cv;
    cv.h = __builtin_amdgcn_cvt_pkrtz(a, b);
    return cv.u;
}

// tanh-form GELU via raw exp2/rcp (max dev from exact erf ~3e-3 << 0.104 threshold).
// exp arg clamped to 120 so e stays finite: v*e*rcp(e+1) -> v for large v (no inf*0 NaN).
__device__ __forceinline__ float gelu_fast(float v) {
    const float u = v * (0.7978845608f + 0.0356774081f * v * v);
    const float e = EXP2R(fminf(u * 2.885390082f, 120.0f));
    return v * e * RCPR(e + 1.0f);
}

// ============ prep: (bid<256) transpose x + double-LN -> t fp32, a_h fp16 ============
// ============       (bid>=256) weight transpose+cast fp32 -> fp16 [N][K]  ============
__global__ __launch_bounds__(256) void prep_kernel(const float* __restrict__ x,
                                                   const float* __restrict__ ln1_g,
                                                   const float* __restrict__ ln1_b,
                                                   const float* __restrict__ lna_g,
                                                   const float* __restrict__ lna_b,
                                                   float* __restrict__ t,
                                                   _Float16* __restrict__ a_h,
                                                   const float* __restrict__ wqkv,
                                                   const float* __restrict__ wout,
                                                   const float* __restrict__ w1,
                                                   const float* __restrict__ w2,
                                                   _Float16* __restrict__ wqkvT,
                                                   _Float16* __restrict__ woutT,
                                                   _Float16* __restrict__ w1T,
                                                   _Float16* __restrict__ w2T) {
    __shared__ float Ts[32][389];
    const int bid = blockIdx.x;
    const int tid = threadIdx.x;

    if (bid >= 256) {
        float (*tile)[33] = (float(*)[33])&Ts[0][0];
        const int wb = bid - 256;
        const float* W; _Float16* Wt; int K, N, nx, tt;
        if (wb < 432)       { W = wqkv; Wt = wqkvT; K = 384;  N = 1152; nx = 36; tt = wb; }
        else if (wb < 576)  { W = wout; Wt = woutT; K = 384;  N = 384;  nx = 12; tt = wb - 432; }
        else if (wb < 1152) { W = w1;   Wt = w1T;   K = 384;  N = 1536; nx = 48; tt = wb - 576; }
        else                { W = w2;   Wt = w2T;   K = 1536; N = 384;  nx = 12; tt = wb - 1152; }
        const int n0 = (tt % nx) * 32, k0 = (tt / nx) * 32;
        const int tx = tid & 31, ty = tid >> 5;
        #pragma unroll
        for (int i = ty; i < 32; i += 8)
            tile[i][tx] = W[(size_t)(k0 + i) * N + n0 + tx];
        __syncthreads();
        #pragma unroll
        for (int i = ty; i < 32; i += 8)
            Wt[(size_t)(n0 + i) * K + k0 + tx] = (_Float16)tile[tx][i];
        return;
    }

    // ---- transpose + double-LN ----
    const int b = bid >> 5, n0 = (bid & 31) * 32;
    const int tx = tid & 31, ty8 = tid >> 5;
    const float* xb = x + (size_t)b * (DM * NTOK);
    #pragma unroll
    for (int c0 = 0; c0 < DM; c0 += 32) {
        #pragma unroll
        for (int i = ty8; i < 32; i += 8)
            Ts[tx][c0 + i] = xb[(size_t)(c0 + i) * NTOK + n0 + tx];
    }
    __syncthreads();

    const int g = tid >> 3, sub = tid & 7;
    const int c0 = sub * 48;
    float xv[48];
    #pragma unroll
    for (int k = 0; k < 12; ++k)
        *(float4*)&xv[k * 4] = *(const float4*)&Ts[g][c0 + k * 4];

    const size_t trow = (size_t)((b << 10) + n0 + g) * DM;
    float s = 0.0f, sq = 0.0f;
    #pragma unroll
    for (int k = 0; k < 12; ++k)
        *(float4*)&t[trow + c0 + k * 4] = *(const float4*)&xv[k * 4];
    #pragma unroll
    for (int j = 0; j < 48; ++j) { s += xv[j]; sq += xv[j] * xv[j]; }
    s += __shfl_xor(s, 1, 64); sq += __shfl_xor(sq, 1, 64);
    s += __shfl_xor(s, 2, 64); sq += __shfl_xor(sq, 2, 64);
    s += __shfl_xor(s, 4, 64); sq += __shfl_xor(sq, 4, 64);
    float mu = s * (1.0f / DM);
    float var = fmaxf(sq * (1.0f / DM) - mu * mu, 0.0f);
    float r1 = rsqrtf(var + 1e-5f);

    float s2 = 0.0f, q2 = 0.0f;
    #pragma unroll
    for (int k = 0; k < 12; ++k) {
        const float4 gk = *(const float4*)&ln1_g[c0 + k * 4];
        const float4 bk = *(const float4*)&ln1_b[c0 + k * 4];
        float y0 = (xv[k*4+0] - mu) * r1 * gk.x + bk.x;
        float y1 = (xv[k*4+1] - mu) * r1 * gk.y + bk.y;
        float y2 = (xv[k*4+2] - mu) * r1 * gk.z + bk.z;
        float y3 = (xv[k*4+3] - mu) * r1 * gk.w + bk.w;
        xv[k*4+0] = y0; xv[k*4+1] = y1; xv[k*4+2] = y2; xv[k*4+3] = y3;
        s2 += (y0 + y1) + (y2 + y3);
        q2 += (y0*y0 + y1*y1) + (y2*y2 + y3*y3);
    }
    s2 += __shfl_xor(s2, 1, 64); q2 += __shfl_xor(q2, 1, 64);
    s2 += __shfl_xor(s2, 2, 64); q2 += __shfl_xor(q2, 2, 64);
    s2 += __shfl_xor(s2, 4, 64); q2 += __shfl_xor(q2, 4, 64);
    mu = s2 * (1.0f / DM);
    var = fmaxf(q2 * (1.0f / DM) - mu * mu, 0.0f);
    const float r2 = rsqrtf(var + 1e-5f);

    unsigned int d[12];
    #pragma unroll
    for (int k = 0; k < 12; ++k) {
        const float4 gk = *(const float4*)&lna_g[c0 + k * 4];
        const float4 bk = *(const float4*)&lna_b[c0 + k * 4];
        const float y0 = (xv[k*4+0] - mu) * r2 * gk.x + bk.x;
        const float y1 = (xv[k*4+1] - mu) * r2 * gk.y + bk.y;
        const float y2 = (xv[k*4+2] - mu) * r2 * gk.z + bk.z;
        const float y3 = (xv[k*4+3] - mu) * r2 * gk.w + bk.w;
        d[k*2+0] = pkh(y0, y1); d[k*2+1] = pkh(y2, y3);
    }
    unsigned int* op = (unsigned int*)(a_h + trow + c0);
    #pragma unroll
    for (int k = 0; k < 3; ++k)
        *(uint4*)(op + k * 4) = *(const uint4*)&d[k * 4];
}

// ---------------- layernorm2: one wave per row (fp32 in, fp16 out) ----------------
__global__ __launch_bounds__(256) void ln2_kernel(const float* __restrict__ in,
                                                  const float* __restrict__ gg,
                                                  const float* __restrict__ bb,
                                                  _Float16* __restrict__ outp) {
    const int row = blockIdx.x * 4 + (threadIdx.x >> 6);
    const int lane = threadIdx.x & 63;
    const float* ip = in + (size_t)row * DM + lane * 6;
    float v[6];
    *(float2*)&v[0] = *(const float2*)(ip);
    *(float2*)&v[2] = *(const float2*)(ip + 2);
    *(float2*)&v[4] = *(const float2*)(ip + 4);
    float s = 0.0f, sq = 0.0f;
    #pragma unroll
    for (int j = 0; j < 6; ++j) { s += v[j]; sq += v[j] * v[j]; }
    #pragma unroll
    for (int off = 1; off < 64; off <<= 1) {
        s += __shfl_xor(s, off, 64);
        sq += __shfl_xor(sq, off, 64);
    }
    const float mu = s * (1.0f / DM);
    const float var = fmaxf(sq * (1.0f / DM) - mu * mu, 0.0f);
    const float rs = rsqrtf(var + 1e-5f);
    const float* gp = gg + lane * 6;
    const float* bp = bb + lane * 6;
    float y[6];
    #pragma unroll
    for (int j = 0; j < 6; ++j) y[j] = (v[j] - mu) * rs * gp[j] + bp[j];
    unsigned int* op = (unsigned int*)(outp + (size_t)row * DM + lane * 6);
    op[0] = pkh(y[0], y[1]); op[1] = pkh(y[2], y[3]); op[2] = pkh(y[4], y[5]);
}

// ---------------- fp16 MFMA GEMM (single-buffer, R7 config = best total) ----------------
// C = A[M,K] @ Bt[N,K]^T.  EPI: 0 plain->fp16; 1 +residual->fp32; 2 +bias,GELU->fp16;
// 4 +bias+residual->fp32 DIRECT-TRANSPOSED out.
template <int EPI, int BN>
__global__ __launch_bounds__(256) void gemm_f16(const _Float16* __restrict__ A,
                                                const _Float16* __restrict__ Bt,
                                                const float* __restrict__ bias,
                                                const float* __restrict__ R,
                                                _Float16* __restrict__ Ch,
                                                float* __restrict__ Cf,
                                                int M, int N, int K) {
    constexpr int NFRAG = BN / 32;
    __shared__ _Float16 As[128][64];
    __shared__ _Float16 Bs[BN][64];
    const int tid = threadIdx.x;
    const int w = tid >> 6, lane = tid & 63;
    const int l15 = lane & 15, lq = lane >> 4;
    const int bm = blockIdx.y * 128, bn = blockIdx.x * BN;
    const int moff = (w & 1) * 64, noff = (w >> 1) * (BN / 2);

    const int srw = lane >> 3, pp = lane & 7;
    const int c = pp ^ srw;
    const _Float16* Ag[4];
    const _Float16* Bg[BN / 32];
    #pragma unroll
    for (int j = 0; j < 4; ++j)
        Ag[j] = A + (size_t)(bm + w * 32 + j * 8 + srw) * K + c * 8;
    #pragma unroll
    for (int j = 0; j < BN / 32; ++j)
        Bg[j] = Bt + (size_t)(bn + w * (BN / 4) + j * 8 + srw) * K + c * 8;

    const int octA = ((lq ^ (l15 & 7)) << 4);

    f32x4 acc[4][NFRAG];
    #pragma unroll
    for (int mi = 0; mi < 4; ++mi)
        #pragma unroll
        for (int ni = 0; ni < NFRAG; ++ni) acc[mi][ni] = (f32x4){0.f, 0.f, 0.f, 0.f};

    for (int k0 = 0; k0 < K; k0 += 64) {
        __syncthreads();
        #pragma unroll
        for (int j = 0; j < 4; ++j) {
            ASYNC16(Ag[j], &As[w * 32 + j * 8][0]);
            Ag[j] += 64;
        }
        #pragma unroll
        for (int j = 0; j < BN / 32; ++j) {
            ASYNC16(Bg[j], &Bs[w * (BN / 4) + j * 8][0]);
            Bg[j] += 64;
        }
        __syncthreads();
        #pragma unroll
        for (int ks = 0; ks < 2; ++ks) {
            const int ox = octA ^ (ks << 6);
            f16x8 af[4], bfr[NFRAG];
            #pragma unroll
            for (int mi = 0; mi < 4; ++mi)
                af[mi] = *(const f16x8*)((const char*)As + ((moff + mi * 16 + l15) << 7) + ox);
            #pragma unroll
            for (int ni = 0; ni < NFRAG; ++ni)
                bfr[ni] = *(const f16x8*)((const char*)Bs + ((noff + ni * 16 + l15) << 7) + ox);
            #pragma unroll
            for (int mi = 0; mi < 4; ++mi)
                #pragma unroll
                for (int ni = 0; ni < NFRAG; ++ni)
                    acc[mi][ni] = __builtin_amdgcn_mfma_f32_16x16x32_f16(af[mi], bfr[ni], acc[mi][ni], 0, 0, 0);
        }
    }

    // epilogue: C/D layout col = lane&15, row = (lane>>4)*4 + r
    #pragma unroll
    for (int mi = 0; mi < 4; ++mi) {
        #pragma unroll
        for (int ni = 0; ni < NFRAG; ++ni) {
            const int col = bn + noff + ni * 16 + l15;
            float bv = 0.0f;
            if (EPI >= 2) bv = bias[col];
            if (EPI == 4) {
                const int row0 = bm + moff + mi * 16 + lq * 4;
                const int b = row0 >> 10, nn = row0 & 1023;
                float4 vv;
                vv.x = acc[mi][ni][0] + bv + R[(size_t)(row0 + 0) * N + col];
                vv.y = acc[mi][ni][1] + bv + R[(size_t)(row0 + 1) * N + col];
                vv.z = acc[mi][ni][2] + bv + R[(size_t)(row0 + 2) * N + col];
                vv.w = acc[mi][ni][3] + bv + R[(size_t)(row0 + 3) * N + col];
                *(float4*)(Cf + (size_t)b * (DM * NTOK) + (size_t)col * NTOK + nn) = vv;
            } else {
                #pragma unroll
                for (int r = 0; r < 4; ++r) {
                    const int row = bm + moff + mi * 16 + lq * 4 + r;
                    const size_t idx = (size_t)row * N + col;
                    float v = acc[mi][ni][r];
                    if (EPI == 2) v = gelu_fast(v + bv);
                    if (EPI == 0 || EPI == 2) Ch[idx] = (_Float16)v;
                    else                      Cf[idx] = v + R[idx];
                }
            }
        }
    }
}

// ---------------- MFMA flash attention v7 (64q, dbuf, raw v_exp) ----------------
// 1024 blocks (4/CU). Wave owns 16 q; Q in registers; K dbuf via global_load_lds;
// V dbuf via regs + deferred LDS write; 1 barrier/ktile; exp = single v_exp_f32.
__global__ __launch_bounds__(256) void attn_kernel(const _Float16* __restrict__ qkv,
                                                   _Float16* __restrict__ o) {
    __shared__ _Float16 Ks[2][64][64];
    __shared__ _Float16 Vt[2][48][72];
    __shared__ _Float16 Ps[4][16][72];
    const int tid = threadIdx.x;
    const int w = tid >> 6, lane = tid & 63;
    const int l15 = lane & 15, lq = lane >> 4;
    const int bid = blockIdx.x;
    const int bh = ((bid >> 3) & 7) * 8 + (bid & 7);   // same (b,h) -> same XCD (mod-8)
    const int qt0 = (bid >> 6) * 64;
    const int h = bh & 7, b = bh >> 3;

    const _Float16* qbase = qkv + (size_t)b * NTOK * 1152 + h * 48;
    const _Float16* kbase = qbase + 384;
    const _Float16* vbase = qbase + 768;

    // ---- Q fragments in registers (feat >= 48 zero -> kills K-pad garbage) ----
    f16x8 qf[2];
    {
        const size_t qrow = (size_t)(qt0 + w * 16 + l15) * 1152;
        qf[0] = *(const f16x8*)(qbase + qrow + lq * 8);
        if (lq < 2) qf[1] = *(const f16x8*)(qbase + qrow + 32 + lq * 8);
        else        qf[1] = (f16x8){(_Float16)0, (_Float16)0, (_Float16)0, (_Float16)0,
                                    (_Float16)0, (_Float16)0, (_Float16)0, (_Float16)0};
    }

    const int srw = lane >> 3, pp = lane & 7;
    const int ck = pp ^ srw;
    const int ckoff = (ck < 6) ? ck * 8 : (ck - 6) * 8;
    const _Float16* Kg = kbase + (size_t)(w * 16 + srw) * 1152 + ckoff;
    const int vtp = tid & 31, vfo = tid >> 5;
    const _Float16* Vg = vbase + (size_t)(vtp * 2) * 1152 + vfo * 8;

    const int octK = ((lq ^ (l15 & 7)) << 4);

    // prologue: prefetch tile 0
    ASYNC16(Kg, &Ks[0][w * 16][0]);
    ASYNC16(Kg + 8 * 1152, &Ks[0][w * 16 + 8][0]);
    Kg += 64 * 1152;
    uint4 va, vb;
    if (vfo < 6) { va = *(const uint4*)Vg; vb = *(const uint4*)(Vg + 1152); }
    Vg += 64 * 1152;

    f32x4 oacc[3];
    float lpart = 0.0f;
    #pragma unroll
    for (int vf = 0; vf < 3; ++vf) oacc[vf] = (f32x4){0.f, 0.f, 0.f, 0.f};

    int cur = 0;
    for (int kt = 0; kt < 16; ++kt) {
        if (vfo < 6) {   // deferred V write (vmcnt wait lands after prev compute)
            const unsigned short* as = (const unsigned short*)&va;
            const unsigned short* bs = (const unsigned short*)&vb;
            #pragma unroll
            for (int j = 0; j < 8; ++j) {
                const unsigned int dw = (unsigned int)as[j] | ((unsigned int)bs[j] << 16);
                *(unsigned int*)((char*)&Vt[cur][0][0] + (vfo * 8 + j) * 144 + vtp * 4) = dw;
            }
        }
        __syncthreads();
        if (kt < 15) {
            ASYNC16(Kg, &Ks[cur ^ 1][w * 16][0]);
            ASYNC16(Kg + 8 * 1152, &Ks[cur ^ 1][w * 16 + 8][0]);
            Kg += 64 * 1152;
            if (vfo < 6) { va = *(const uint4*)Vg; vb = *(const uint4*)(Vg + 1152); }
            Vg += 64 * 1152;
        }

        // ---- S^T = K @ Q^T (4 kpos-tiles) ----
        f32x4 sacc[4];
        #pragma unroll
        for (int mi = 0; mi < 4; ++mi) sacc[mi] = (f32x4){0.f, 0.f, 0.f, 0.f};
        #pragma unroll
        for (int ks = 0; ks < 2; ++ks) {
            const int ox = octK ^ (ks << 6);
            #pragma unroll
            for (int mi = 0; mi < 4; ++mi) {
                const f16x8 kf = *(const f16x8*)((const char*)&Ks[cur][0][0] + ((mi * 16 + l15) << 7) + ox);
                sacc[mi] = __builtin_amdgcn_mfma_f32_16x16x32_f16(kf, qf[ks], sacc[mi], 0, 0, 0);
            }
        }

        // ---- exp2 via raw v_exp (no max-sub), partial l, pack P (wave-private) ----
        #pragma unroll
        for (int mi = 0; mi < 4; ++mi) {
            const float p0 = EXP2R(sacc[mi][0] * SC2);
            const float p1 = EXP2R(sacc[mi][1] * SC2);
            const float p2 = EXP2R(sacc[mi][2] * SC2);
            const float p3 = EXP2R(sacc[mi][3] * SC2);
            lpart += (p0 + p1) + (p2 + p3);
            uint2 d;
            d.x = pkh(p0, p1); d.y = pkh(p2, p3);
            *(uint2*)((char*)&Ps[w][0][0] + l15 * 144 + (mi * 16 + lq * 4) * 2) = d;
        }
        asm volatile("s_waitcnt lgkmcnt(0)" ::: "memory");

        // ---- O^T += V^T @ P ----
        #pragma unroll
        for (int ks = 0; ks < 2; ++ks) {
            const int kk2 = ks * 64 + lq * 16;
            const f16x8 pf = *(const f16x8*)((const char*)&Ps[w][0][0] + l15 * 144 + kk2);
            #pragma unroll
            for (int vf = 0; vf < 3; ++vf) {
                const f16x8 vv = *(const f16x8*)((const char*)&Vt[cur][0][0] + (vf * 16 + l15) * 144 + kk2);
                oacc[vf] = __builtin_amdgcn_mfma_f32_16x16x32_f16(vv, pf, oacc[vf], 0, 0, 0);
            }
        }
        cur ^= 1;
    }

    // ---- normalize + write ----
    lpart += __shfl_xor(lpart, 16, 64);
    lpart += __shfl_xor(lpart, 32, 64);
    const float linv = RCPR(lpart);
    _Float16* ob = o + (size_t)(b * NTOK + qt0 + w * 16 + l15) * DM + h * DH;
    #pragma unroll
    for (int vf = 0; vf < 3; ++vf) {
        uint2 d;
        d.x = pkh(oacc[vf][0] * linv, oacc[vf][1] * linv);
        d.y = pkh(oacc[vf][2] * linv, oacc[vf][3] * linv);
        *(uint2*)(ob + vf * 16 + lq * 4) = d;
    }
}

extern "C" void kernel_launch(void* const* d_in, const int* in_sizes, int n_in,
                              void* d_out, int out_size, void* d_ws, size_t ws_size,
                              hipStream_t stream) {
    const float* x     = (const float*)d_in[0];
    const float* ln1_g = (const float*)d_in[1];
    const float* ln1_b = (const float*)d_in[2];
    const float* lna_g = (const float*)d_in[3];
    const float* lna_b = (const float*)d_in[4];
    const float* w_qkv = (const float*)d_in[5];
    const float* w_out = (const float*)d_in[6];
    const float* ln2_g = (const float*)d_in[7];
    const float* ln2_b = (const float*)d_in[8];
    const float* w1    = (const float*)d_in[9];
    const float* b1    = (const float*)d_in[10];
    const float* w2    = (const float*)d_in[11];
    const float* b2    = (const float*)d_in[12];
    float* out = (float*)d_out;

    char* wsb = (char*)d_ws;
    float* t          = (float*)(wsb);                 // 12,582,912 B
    _Float16* a_h     = (_Float16*)(wsb + 12582912);   //  6,291,456
    _Float16* qkv_h   = (_Float16*)(wsb + 18874368);   // 18,874,368
    _Float16* o_h     = (_Float16*)(wsb + 37748736);   //  6,291,456
    _Float16* h1_h    = (_Float16*)(wsb + 44040192);   // 25,165,824
    _Float16* wqkvT   = (_Float16*)(wsb + 69206016);   //    884,736
    _Float16* woutT   = (_Float16*)(wsb + 70090752);   //    294,912
    _Float16* w1T     = (_Float16*)(wsb + 70385664);   //  1,179,648
    _Float16* w2T     = (_Float16*)(wsb + 71565312);   //  1,179,648

    // 1. fused: transpose+LN+LN -> t, a_h ; weight prep -> *T
    prep_kernel<<<256 + 1728, 256, 0, stream>>>(x, ln1_g, ln1_b, lna_g, lna_b, t, a_h,
                                                w_qkv, w_out, w1, w2, wqkvT, woutT, w1T, w2T);
    // 2. qkv_h = a @ w_qkv
    gemm_f16<0, 128><<<dim3(9, 64), 256, 0, stream>>>(a_h, wqkvT, nullptr, nullptr, qkv_h, nullptr, NROWS, 3 * DM, DM);
    // 3. o_h = attention(qkv_h)
    attn_kernel<<<1024, 256, 0, stream>>>(qkv_h, o_h);
    // 4. t = t + o @ w_out
    gemm_f16<1, 64><<<dim3(6, 64), 256, 0, stream>>>(o_h, woutT, nullptr, t, nullptr, t, NROWS, DM, DM);
    // 5. a_h = fp16(LN(t))
    ln2_kernel<<<2048, 256, 0, stream>>>(t, ln2_g, ln2_b, a_h);
    // 6. h1_h = gelu(a @ w1 + b1)
    gemm_f16<2, 128><<<dim3(12, 64), 256, 0, stream>>>(a_h, w1T, b1, nullptr, h1_h, nullptr, NROWS, 4 * DM, DM);
    // 7. out[b,c,n] = (t + h1 @ w2 + b2) transposed, written directly
    gemm_f16<4, 64><<<dim3(6, 64), 256, 0, stream>>>(h1_h, w2T, b2, t, nullptr, out, NROWS, DM, 4 * DM);
}